// Round 17
// baseline (60.828 us; speedup 1.0000x reference)
//
#include <hip/hip_runtime.h>
#include <hip/hip_bf16.h>
#include <math.h>

#define DD 256      // feature dim
#define SS 1024     // seq len
#define BB 8        // batch
#define NN 128      // nodes
#define TOK 16      // tokens per fallback-scorer block
#define KC 64       // k-chunk staged in LDS (fallback scorer)
#define NT 8        // nodes per pool tile
#define SC 8        // S-chunks in pool
#define SCH (SS/SC) // 128

typedef __attribute__((ext_vector_type(8))) short short8;
typedef __attribute__((ext_vector_type(4))) float f32x4;

__device__ __forceinline__ unsigned short f2bf(float x) {
    unsigned u = __builtin_bit_cast(unsigned, x);
    u += 0x7fffu + ((u >> 16) & 1u);          // round-to-nearest-even
    return (unsigned short)(u >> 16);
}
__device__ __forceinline__ float bf2f(unsigned short h) {
    return __builtin_bit_cast(float, (unsigned)h << 16);
}
// 8 contiguous f32 -> bf16 hi/lo fragments (r10-verified conversion)
__device__ __forceinline__ void cvt8(const float* __restrict__ p, short8& hi, short8& lo) {
    const float4 xa = *reinterpret_cast<const float4*>(p);
    const float4 xb = *reinterpret_cast<const float4*>(p + 4);
    unsigned short h;
    h = f2bf(xa.x); hi[0] = (short)h; lo[0] = (short)f2bf(xa.x - bf2f(h));
    h = f2bf(xa.y); hi[1] = (short)h; lo[1] = (short)f2bf(xa.y - bf2f(h));
    h = f2bf(xa.z); hi[2] = (short)h; lo[2] = (short)f2bf(xa.z - bf2f(h));
    h = f2bf(xa.w); hi[3] = (short)h; lo[3] = (short)f2bf(xa.w - bf2f(h));
    h = f2bf(xb.x); hi[4] = (short)h; lo[4] = (short)f2bf(xb.x - bf2f(h));
    h = f2bf(xb.y); hi[5] = (short)h; lo[5] = (short)f2bf(xb.y - bf2f(h));
    h = f2bf(xb.z); hi[6] = (short)h; lo[6] = (short)f2bf(xb.z - bf2f(h));
    h = f2bf(xb.w); hi[7] = (short)h; lo[7] = (short)f2bf(xb.w - bf2f(h));
}

// ============ Kernel 0 (verified): W1 -> W1T hi/lo (transposed) ============
__global__ __launch_bounds__(256) void split_w1t_kernel(
    const float* __restrict__ W1,
    unsigned short* __restrict__ w1t_hi, unsigned short* __restrict__ w1t_lo)
{
    __shared__ float tl[64][65];
    const int tid = threadIdx.x;
    const int k0 = (blockIdx.x >> 2) * 64, n0 = (blockIdx.x & 3) * 64;
#pragma unroll
    for (int i = 0; i < 16; ++i) {
        const int idx = i * 256 + tid;
        const int r = idx >> 6, c = idx & 63;
        tl[r][c] = W1[(size_t)(k0 + r) * DD + n0 + c];
    }
    __syncthreads();
#pragma unroll
    for (int i = 0; i < 16; ++i) {
        const int idx = i * 256 + tid;
        const int nl = idx >> 6, kl = idx & 63;
        const float v = tl[kl][nl];
        const unsigned short h = f2bf(v);
        const size_t o = (size_t)(n0 + nl) * DD + k0 + kl;
        w1t_hi[o] = h;
        w1t_lo[o] = f2bf(v - bf2f(h));
    }
}

// ============ Kernel 1: MFMA scorer GEMM, A converted in-register ============
// grid 1024 (4 blocks/CU): token-tile (blk>>2, 32 tokens) x col-tile (blk&3, 64 cols).
// Wave owns 32 tok x 16 cols (2 M-tiles). Split-bf16 x3. [r11-verified layout]
__global__ __launch_bounds__(256) void scorer_gemm_kernel(
    const float* __restrict__ doc,
    const unsigned short* __restrict__ w1t_hi, const unsigned short* __restrict__ w1t_lo,
    float* __restrict__ hbuf)
{
    const int tid  = threadIdx.x;
    const int wave = tid >> 6, lane = tid & 63;
    const int l15  = lane & 15, kg = lane >> 4;
    const int t0 = (blockIdx.x >> 2) * 32;
    const int n0 = (blockIdx.x & 3) * 64 + wave * 16;

    const f32x4 z = {0.f, 0.f, 0.f, 0.f};
    f32x4 acc0 = z, acc1 = z;

    const float* arow0 = doc + (size_t)(t0 + l15) * DD;
    const float* arow1 = doc + (size_t)(t0 + 16 + l15) * DD;
    const size_t brow  = (size_t)(n0 + l15) * DD;

#pragma unroll
    for (int ks = 0; ks < 8; ++ks) {
        const int k = ks * 32 + kg * 8;
        short8 a0h, a0l, a1h, a1l;
        cvt8(arow0 + k, a0h, a0l);
        cvt8(arow1 + k, a1h, a1l);
        const short8 bh = *reinterpret_cast<const short8*>(w1t_hi + brow + k);
        const short8 bl = *reinterpret_cast<const short8*>(w1t_lo + brow + k);
        acc0 = __builtin_amdgcn_mfma_f32_16x16x32_bf16(a0h, bh, acc0, 0, 0, 0);
        acc0 = __builtin_amdgcn_mfma_f32_16x16x32_bf16(a0h, bl, acc0, 0, 0, 0);
        acc0 = __builtin_amdgcn_mfma_f32_16x16x32_bf16(a0l, bh, acc0, 0, 0, 0);
        acc1 = __builtin_amdgcn_mfma_f32_16x16x32_bf16(a1h, bh, acc1, 0, 0, 0);
        acc1 = __builtin_amdgcn_mfma_f32_16x16x32_bf16(a1h, bl, acc1, 0, 0, 0);
        acc1 = __builtin_amdgcn_mfma_f32_16x16x32_bf16(a1l, bh, acc1, 0, 0, 0);
    }
    // C/D: col = lane&15 (B row), row = (lane>>4)*4 + reg (A row)  [m89-verified]
#pragma unroll
    for (int r = 0; r < 4; ++r) {
        hbuf[(size_t)(t0 + kg * 4 + r) * DD + n0 + l15]      = acc0[r];
        hbuf[(size_t)(t0 + 16 + kg * 4 + r) * DD + n0 + l15] = acc1[r];
    }
}

// ============ Kernel 2 (r9/r11 verbatim, PASSED): combine = +b1, LN, GELU, @W2 ============
__global__ __launch_bounds__(256) void combine_kernel(
    const float* __restrict__ hbuf, const float* __restrict__ b1,
    const float* __restrict__ gamma, const float* __restrict__ beta,
    const float* __restrict__ W2, const float* __restrict__ b2,
    float* __restrict__ scores)
{
    const int tid  = threadIdx.x;
    const int wave = tid >> 6, lane = tid & 63;
    const int t0   = blockIdx.x * 16;
    const int c0   = lane * 4;

    const float4 bv  = *reinterpret_cast<const float4*>(b1 + c0);
    const float4 gm  = *reinterpret_cast<const float4*>(gamma + c0);
    const float4 be  = *reinterpret_cast<const float4*>(beta + c0);
    const float4 w2v = *reinterpret_cast<const float4*>(W2 + c0);
    const float  b2v = b2[0];

#pragma unroll
    for (int t = 0; t < 4; ++t) {
        const int row = t0 + wave * 4 + t;
        float4 h = *reinterpret_cast<const float4*>(hbuf + (size_t)row * DD + c0);
        h.x += bv.x; h.y += bv.y; h.z += bv.z; h.w += bv.w;

        float s1 = h.x + h.y + h.z + h.w;
        float s2 = h.x * h.x + h.y * h.y + h.z * h.z + h.w * h.w;
#pragma unroll
        for (int off = 32; off > 0; off >>= 1) {
            s1 += __shfl_xor(s1, off, 64);
            s2 += __shfl_xor(s2, off, 64);
        }
        const float mean = s1 * (1.f / DD);
        const float var  = s2 * (1.f / DD) - mean * mean;
        const float inv  = rsqrtf(var + 1e-5f);

        const float n0 = (h.x - mean) * inv * gm.x + be.x;
        const float n1 = (h.y - mean) * inv * gm.y + be.y;
        const float n2 = (h.z - mean) * inv * gm.z + be.z;
        const float n3 = (h.w - mean) * inv * gm.w + be.w;
        const float kq = 0.70710678118654752f;
        const float g0 = 0.5f * n0 * (1.f + erff(n0 * kq));
        const float g1 = 0.5f * n1 * (1.f + erff(n1 * kq));
        const float g2 = 0.5f * n2 * (1.f + erff(n2 * kq));
        const float g3 = 0.5f * n3 * (1.f + erff(n3 * kq));
        float sc = g0 * w2v.x + g1 * w2v.y + g2 * w2v.z + g3 * w2v.w;
#pragma unroll
        for (int off = 32; off > 0; off >>= 1) sc += __shfl_xor(sc, off, 64);
        if (lane == 0) scores[row] = sc + b2v;
    }
}

// ====== Kernel 3 (r16 verbatim, PASSED): pool with inline softmax-numerator ======
__global__ __launch_bounds__(256) void pool_e_kernel(
    const float* __restrict__ doc, const float* __restrict__ mapping,
    const float* __restrict__ scores, float* __restrict__ part,
    float* __restrict__ zpart)
{
    __shared__ float w_lds[NT][SCH];   // 4 KiB
    __shared__ float z_s[NT];

    const int blk   = blockIdx.x;
    const int c     = blk % SC;
    const int bt    = blk / SC;
    const int ntile = bt & 15;
    const int b     = bt >> 4;
    const int s0    = c * SCH;
    const int tid = threadIdx.x, wave = tid >> 6, lane = tid & 63;

    {
        const int nl = wave * 2 + (lane >> 5);
        const int g  = b * NN + ntile * NT + nl;
        const float4 mp = reinterpret_cast<const float4*>(mapping + (size_t)g * SS + s0)[lane & 31];
        const float4 sv = reinterpret_cast<const float4*>(scores + (size_t)b * SS + s0)[lane & 31];
        float4 e;
        e.x = (mp.x > 0.5f) ? __expf(sv.x) : 0.f;
        e.y = (mp.y > 0.5f) ? __expf(sv.y) : 0.f;
        e.z = (mp.z > 0.5f) ? __expf(sv.z) : 0.f;
        e.w = (mp.w > 0.5f) ? __expf(sv.w) : 0.f;
        reinterpret_cast<float4*>(&w_lds[nl][0])[lane & 31] = e;
        float z = e.x + e.y + e.z + e.w;
#pragma unroll
        for (int off = 16; off > 0; off >>= 1) z += __shfl_xor(z, off, 64);
        if ((lane & 31) == 0) z_s[nl] = z;
    }
    __syncthreads();

    float acc[NT];
#pragma unroll
    for (int n = 0; n < NT; ++n) acc[n] = 0.f;
    const float* docb = doc + ((size_t)b * SS + s0) * DD;

    float d0 = docb[(size_t)0 * DD + tid], d1 = docb[(size_t)1 * DD + tid];
    float d2 = docb[(size_t)2 * DD + tid], d3 = docb[(size_t)3 * DD + tid];
    for (int s4 = 0; s4 < SCH - 4; s4 += 4) {
        const float n0 = docb[(size_t)(s4 + 4) * DD + tid];
        const float n1 = docb[(size_t)(s4 + 5) * DD + tid];
        const float n2 = docb[(size_t)(s4 + 6) * DD + tid];
        const float n3 = docb[(size_t)(s4 + 7) * DD + tid];
#pragma unroll
        for (int n = 0; n < NT; ++n) {
            const float4 wv = *reinterpret_cast<const float4*>(&w_lds[n][s4]);
            acc[n] = fmaf(wv.x, d0, acc[n]);
            acc[n] = fmaf(wv.y, d1, acc[n]);
            acc[n] = fmaf(wv.z, d2, acc[n]);
            acc[n] = fmaf(wv.w, d3, acc[n]);
        }
        d0 = n0; d1 = n1; d2 = n2; d3 = n3;
    }
    {
        const int s4 = SCH - 4;
#pragma unroll
        for (int n = 0; n < NT; ++n) {
            const float4 wv = *reinterpret_cast<const float4*>(&w_lds[n][s4]);
            acc[n] = fmaf(wv.x, d0, acc[n]);
            acc[n] = fmaf(wv.y, d1, acc[n]);
            acc[n] = fmaf(wv.z, d2, acc[n]);
            acc[n] = fmaf(wv.w, d3, acc[n]);
        }
    }

    float* p = part + (size_t)blk * (NT * DD);
#pragma unroll
    for (int n = 0; n < NT; ++n) p[(size_t)n * DD + tid] = acc[n];
    if (tid < NT) zpart[(size_t)blk * NT + tid] = z_s[tid];
}

// ---------------- Kernel 4 (r16 verbatim, PASSED): reduce + divide ----------------
__global__ __launch_bounds__(256) void reduce_div_kernel(
    const float* __restrict__ part, const float* __restrict__ zpart,
    float* __restrict__ out)
{
    const int o = blockIdx.x * 256 + threadIdx.x;
    const int d = o & 255;
    const int g = o >> 8;
    const int b = g >> 7;
    const int n = g & 127;
    const int ntile = n >> 3, nl = n & 7;
    const int bp0 = (b * 16 + ntile) * SC;
    float s = 0.f, z = 0.f;
#pragma unroll
    for (int c = 0; c < SC; ++c) {
        const int bp = bp0 + c;
        s += part[(size_t)bp * (NT * DD) + (size_t)nl * DD + d];
        z += zpart[(size_t)bp * NT + nl];
    }
    out[o] = (z > 0.f) ? (s / z) : 0.f;
}

// ================= Fallback path (tiny ws): r5/r16 verified kernels =================
__global__ __launch_bounds__(256) void scorer_kernel(
    const float* __restrict__ doc, const float* __restrict__ W1,
    const float* __restrict__ b1, const float* __restrict__ gamma,
    const float* __restrict__ beta, const float* __restrict__ W2,
    const float* __restrict__ b2, float* __restrict__ scores)
{
    __shared__ float xs[TOK][DD];
    __shared__ float w1s[KC][DD];

    const int tid  = threadIdx.x;
    const int wave = tid >> 6, lane = tid & 63;
    const int t0   = blockIdx.x * TOK;
    const int c0   = lane * 4;

    {
        const float4* src = reinterpret_cast<const float4*>(doc + (size_t)t0 * DD);
        float4* dst = reinterpret_cast<float4*>(&xs[0][0]);
#pragma unroll
        for (int r = 0; r < 4; ++r) dst[tid + 256 * r] = src[tid + 256 * r];
    }

    float4 acc[4];
    {
        const float4 bv = *reinterpret_cast<const float4*>(b1 + c0);
#pragma unroll
        for (int t = 0; t < 4; ++t) acc[t] = bv;
    }
    const float* xw = &xs[wave * 4][0];

    for (int kc = 0; kc < DD / KC; ++kc) {
        __syncthreads();
        {
            const float4* wsrc = reinterpret_cast<const float4*>(W1 + (size_t)kc * KC * DD);
            float4* wdst = reinterpret_cast<float4*>(&w1s[0][0]);
#pragma unroll
            for (int r = 0; r < 16; ++r) wdst[tid + 256 * r] = wsrc[tid + 256 * r];
        }
        __syncthreads();
#pragma unroll 4
        for (int k4 = 0; k4 < KC / 4; ++k4) {
            const int kb = k4 * 4;
            const float4 w0 = *reinterpret_cast<const float4*>(&w1s[kb + 0][c0]);
            const float4 w1 = *reinterpret_cast<const float4*>(&w1s[kb + 1][c0]);
            const float4 w2 = *reinterpret_cast<const float4*>(&w1s[kb + 2][c0]);
            const float4 w3 = *reinterpret_cast<const float4*>(&w1s[kb + 3][c0]);
#pragma unroll
            for (int t = 0; t < 4; ++t) {
                const float4 xv = *reinterpret_cast<const float4*>(xw + (size_t)t * DD + kc * KC + kb);
                acc[t].x = fmaf(xv.x, w0.x, acc[t].x);
                acc[t].y = fmaf(xv.x, w0.y, acc[t].y);
                acc[t].z = fmaf(xv.x, w0.z, acc[t].z);
                acc[t].w = fmaf(xv.x, w0.w, acc[t].w);
                acc[t].x = fmaf(xv.y, w1.x, acc[t].x);
                acc[t].y = fmaf(xv.y, w1.y, acc[t].y);
                acc[t].z = fmaf(xv.y, w1.z, acc[t].z);
                acc[t].w = fmaf(xv.y, w1.w, acc[t].w);
                acc[t].x = fmaf(xv.z, w2.x, acc[t].x);
                acc[t].y = fmaf(xv.z, w2.y, acc[t].y);
                acc[t].z = fmaf(xv.z, w2.z, acc[t].z);
                acc[t].w = fmaf(xv.z, w2.w, acc[t].w);
                acc[t].x = fmaf(xv.w, w3.x, acc[t].x);
                acc[t].y = fmaf(xv.w, w3.y, acc[t].y);
                acc[t].z = fmaf(xv.w, w3.z, acc[t].z);
                acc[t].w = fmaf(xv.w, w3.w, acc[t].w);
            }
        }
    }

    const float4 gm = *reinterpret_cast<const float4*>(gamma + c0);
    const float4 be = *reinterpret_cast<const float4*>(beta + c0);
    const float4 w2v = *reinterpret_cast<const float4*>(W2 + c0);
    const float b2v = b2[0];

#pragma unroll
    for (int t = 0; t < 4; ++t) {
        float s1 = acc[t].x + acc[t].y + acc[t].z + acc[t].w;
        float s2 = acc[t].x * acc[t].x + acc[t].y * acc[t].y
                 + acc[t].z * acc[t].z + acc[t].w * acc[t].w;
#pragma unroll
        for (int off = 32; off > 0; off >>= 1) {
            s1 += __shfl_xor(s1, off, 64);
            s2 += __shfl_xor(s2, off, 64);
        }
        const float mean = s1 * (1.f / DD);
        const float var  = s2 * (1.f / DD) - mean * mean;
        const float inv  = rsqrtf(var + 1e-5f);
        float n0 = (acc[t].x - mean) * inv * gm.x + be.x;
        float n1 = (acc[t].y - mean) * inv * gm.y + be.y;
        float n2 = (acc[t].z - mean) * inv * gm.z + be.z;
        float n3 = (acc[t].w - mean) * inv * gm.w + be.w;
        const float kq = 0.70710678118654752f;
        float g0 = 0.5f * n0 * (1.f + erff(n0 * kq));
        float g1 = 0.5f * n1 * (1.f + erff(n1 * kq));
        float g2 = 0.5f * n2 * (1.f + erff(n2 * kq));
        float g3 = 0.5f * n3 * (1.f + erff(n3 * kq));
        float sc = g0 * w2v.x + g1 * w2v.y + g2 * w2v.z + g3 * w2v.w;
#pragma unroll
        for (int off = 32; off > 0; off >>= 1) sc += __shfl_xor(sc, off, 64);
        if (lane == 0) scores[t0 + wave * 4 + t] = sc + b2v;
    }
}

extern "C" void kernel_launch(void* const* d_in, const int* in_sizes, int n_in,
                              void* d_out, int out_size, void* d_ws, size_t ws_size,
                              hipStream_t stream) {
    const float* doc     = (const float*)d_in[0];  // (B,S,D)
    const float* mapping = (const float*)d_in[1];  // (B,N,S)
    // d_in[2] = nodes_len (unused)
    const float* W1    = (const float*)d_in[3];    // (D,D)
    const float* b1    = (const float*)d_in[4];    // (D)
    const float* gamma = (const float*)d_in[5];    // (D)
    const float* beta  = (const float*)d_in[6];    // (D)
    const float* W2    = (const float*)d_in[7];    // (D,1)
    const float* b2    = (const float*)d_in[8];    // (1)
    float* out = (float*)d_out;                    // (B,N,D)

    char* base = (char*)d_ws;
    size_t off = 0;
    float* scores = (float*)(base + off); off += (size_t)BB * SS * 4;                   // 32 KiB
    float* part   = (float*)(base + off); off += (size_t)BB * 16 * SC * NT * DD * 4;    // 8 MiB
    float* zpart  = (float*)(base + off); off += (size_t)BB * 16 * SC * NT * 4;         // 32 KiB
    float* hbuf   = (float*)(base + off); off += (size_t)BB * SS * DD * 4;              // 8 MiB
    unsigned short* w1t_hi = (unsigned short*)(base + off); off += (size_t)DD * DD * 2; // 128 KiB
    unsigned short* w1t_lo = (unsigned short*)(base + off); off += (size_t)DD * DD * 2; // 128 KiB
    const size_t need = off;
    const size_t need_min = (size_t)(BB * SS) * 4
                          + (size_t)BB * 16 * SC * NT * DD * 4
                          + (size_t)BB * 16 * SC * NT * 4;

    if (ws_size >= need) {
        split_w1t_kernel<<<16, 256, 0, stream>>>(W1, w1t_hi, w1t_lo);
        scorer_gemm_kernel<<<1024, 256, 0, stream>>>(doc, w1t_hi, w1t_lo, hbuf);
        combine_kernel<<<512, 256, 0, stream>>>(hbuf, b1, gamma, beta, W2, b2, scores);
        pool_e_kernel<<<BB * 16 * SC, 256, 0, stream>>>(doc, mapping, scores, part, zpart);
        reduce_div_kernel<<<(BB * NN * DD) / 256, 256, 0, stream>>>(part, zpart, out);
    } else if (ws_size >= need_min) {
        scorer_kernel<<<BB * SS / TOK, 256, 0, stream>>>(doc, W1, b1, gamma, beta, W2, b2, scores);
        pool_e_kernel<<<BB * 16 * SC, 256, 0, stream>>>(doc, mapping, scores, part, zpart);
        reduce_div_kernel<<<(BB * NN * DD) / 256, 256, 0, stream>>>(part, zpart, out);
    }
}

// Round 18
// 44.188 us; speedup vs baseline: 1.3766x; 1.3766x over previous
//
#include <hip/hip_runtime.h>
#include <hip/hip_bf16.h>
#include <math.h>

#define DD 256      // feature dim
#define SS 1024     // seq len
#define BB 8        // batch
#define NN 128      // nodes
#define TOK 16      // tokens per fallback-scorer block
#define KC 64       // k-chunk staged in LDS (fallback scorer)
#define NT 8        // nodes per pool tile
#define SC 8        // S-chunks in pool
#define SCH (SS/SC) // 128
#define BK 64       // k-chunk in MFMA scorer
#define LDP 72      // padded LDS row stride (bf16 elems): 64 + 8 -> 144B rows

typedef __attribute__((ext_vector_type(8))) short short8;
typedef __attribute__((ext_vector_type(4))) float f32x4;

__device__ __forceinline__ unsigned short f2bf(float x) {
    unsigned u = __builtin_bit_cast(unsigned, x);
    u += 0x7fffu + ((u >> 16) & 1u);          // round-to-nearest-even
    return (unsigned short)(u >> 16);
}
__device__ __forceinline__ float bf2f(unsigned short h) {
    return __builtin_bit_cast(float, (unsigned)h << 16);
}

// ============ Kernel 0 (verified): W1 -> W1T hi/lo (transposed) ============
__global__ __launch_bounds__(256) void split_w1t_kernel(
    const float* __restrict__ W1,
    unsigned short* __restrict__ w1t_hi, unsigned short* __restrict__ w1t_lo)
{
    __shared__ float tl[64][65];
    const int tid = threadIdx.x;
    const int k0 = (blockIdx.x >> 2) * 64, n0 = (blockIdx.x & 3) * 64;
#pragma unroll
    for (int i = 0; i < 16; ++i) {
        const int idx = i * 256 + tid;
        const int r = idx >> 6, c = idx & 63;
        tl[r][c] = W1[(size_t)(k0 + r) * DD + n0 + c];
    }
    __syncthreads();
#pragma unroll
    for (int i = 0; i < 16; ++i) {
        const int idx = i * 256 + tid;
        const int nl = idx >> 6, kl = idx & 63;
        const float v = tl[kl][nl];
        const unsigned short h = f2bf(v);
        const size_t o = (size_t)(n0 + nl) * DD + k0 + kl;
        w1t_hi[o] = h;
        w1t_lo[o] = f2bf(v - bf2f(h));
    }
}

// ============ Kernel 1: MFMA scorer GEMM with LDS-staged operands ============
// grid 1024: mtile = blk>>2 (32 tokens), ntile = blk&3 (64 cols). 4 waves;
// wave owns 32 tok x 16 cols (2 M-tiles) — C-write verbatim from r11/r17 (PASSED).
// K-loop: 4 chunks of BK=64. A staged f32->bf16 hi/lo in-register; B pre-split.
// LDS rows padded to 72 bf16 (144B) -> near-optimal bank usage on ds_read_b128.
__global__ __launch_bounds__(256) void scorer_gemm_staged(
    const float* __restrict__ doc,
    const unsigned short* __restrict__ w1t_hi, const unsigned short* __restrict__ w1t_lo,
    float* __restrict__ hbuf)
{
    __shared__ unsigned short As_hi[32][LDP], As_lo[32][LDP];   // 9.2 KB
    __shared__ unsigned short Bs_hi[64][LDP], Bs_lo[64][LDP];   // 18.4 KB

    const int tid  = threadIdx.x;
    const int wave = tid >> 6, lane = tid & 63;
    const int l15  = lane & 15, kg = lane >> 4;
    const int t0    = (blockIdx.x >> 2) * 32;
    const int nbase = (blockIdx.x & 3) * 64;
    const int n0    = nbase + wave * 16;

    const f32x4 z = {0.f, 0.f, 0.f, 0.f};
    f32x4 acc0 = z, acc1 = z;

    for (int kc = 0; kc < DD / BK; ++kc) {
        const int kbase = kc * BK;
        // ---- stage A: 32x64 f32 -> hi/lo. 512 float4; thread does 2. ----
#pragma unroll
        for (int it = 0; it < 2; ++it) {
            const int idx = tid + it * 256;
            const int r   = idx >> 4;            // 0..31
            const int c4  = (idx & 15) * 4;      // 0..60
            const float4 v = *reinterpret_cast<const float4*>(
                doc + (size_t)(t0 + r) * DD + kbase + c4);
            ushort4 h4, l4;
            h4.x = f2bf(v.x); l4.x = f2bf(v.x - bf2f(h4.x));
            h4.y = f2bf(v.y); l4.y = f2bf(v.y - bf2f(h4.y));
            h4.z = f2bf(v.z); l4.z = f2bf(v.z - bf2f(h4.z));
            h4.w = f2bf(v.w); l4.w = f2bf(v.w - bf2f(h4.w));
            *reinterpret_cast<ushort4*>(&As_hi[r][c4]) = h4;
            *reinterpret_cast<ushort4*>(&As_lo[r][c4]) = l4;
        }
        // ---- stage B: 64x64 bf16 hi+lo. 512 ushort8 per buf; thread does 2+2. ----
#pragma unroll
        for (int it = 0; it < 2; ++it) {
            const int idx = tid + it * 256;
            const int r   = idx >> 3;            // 0..63
            const int c8  = (idx & 7) * 8;       // 0..56
            const size_t g = (size_t)(nbase + r) * DD + kbase + c8;
            *reinterpret_cast<short8*>(&Bs_hi[r][c8]) =
                *reinterpret_cast<const short8*>(w1t_hi + g);
            *reinterpret_cast<short8*>(&Bs_lo[r][c8]) =
                *reinterpret_cast<const short8*>(w1t_lo + g);
        }
        __syncthreads();

        // ---- compute: 2 ksteps of 32 ----
#pragma unroll
        for (int ks = 0; ks < 2; ++ks) {
            const int ko = ks * 32 + kg * 8;
            const short8 a0h = *reinterpret_cast<const short8*>(&As_hi[l15][ko]);
            const short8 a0l = *reinterpret_cast<const short8*>(&As_lo[l15][ko]);
            const short8 a1h = *reinterpret_cast<const short8*>(&As_hi[16 + l15][ko]);
            const short8 a1l = *reinterpret_cast<const short8*>(&As_lo[16 + l15][ko]);
            const short8 bh  = *reinterpret_cast<const short8*>(&Bs_hi[wave * 16 + l15][ko]);
            const short8 bl  = *reinterpret_cast<const short8*>(&Bs_lo[wave * 16 + l15][ko]);
            acc0 = __builtin_amdgcn_mfma_f32_16x16x32_bf16(a0h, bh, acc0, 0, 0, 0);
            acc0 = __builtin_amdgcn_mfma_f32_16x16x32_bf16(a0h, bl, acc0, 0, 0, 0);
            acc0 = __builtin_amdgcn_mfma_f32_16x16x32_bf16(a0l, bh, acc0, 0, 0, 0);
            acc1 = __builtin_amdgcn_mfma_f32_16x16x32_bf16(a1h, bh, acc1, 0, 0, 0);
            acc1 = __builtin_amdgcn_mfma_f32_16x16x32_bf16(a1h, bl, acc1, 0, 0, 0);
            acc1 = __builtin_amdgcn_mfma_f32_16x16x32_bf16(a1l, bh, acc1, 0, 0, 0);
        }
        __syncthreads();   // all waves done reading before next-chunk ds_writes
    }

    // C/D: col = lane&15 (B row), row = (lane>>4)*4 + reg (A row)  [m89-verified]
#pragma unroll
    for (int r = 0; r < 4; ++r) {
        hbuf[(size_t)(t0 + kg * 4 + r) * DD + n0 + l15]      = acc0[r];
        hbuf[(size_t)(t0 + 16 + kg * 4 + r) * DD + n0 + l15] = acc1[r];
    }
}

// ============ Kernel 2 (r9/r11 verbatim, PASSED): combine = +b1, LN, GELU, @W2 ============
__global__ __launch_bounds__(256) void combine_kernel(
    const float* __restrict__ hbuf, const float* __restrict__ b1,
    const float* __restrict__ gamma, const float* __restrict__ beta,
    const float* __restrict__ W2, const float* __restrict__ b2,
    float* __restrict__ scores)
{
    const int tid  = threadIdx.x;
    const int wave = tid >> 6, lane = tid & 63;
    const int t0   = blockIdx.x * 16;
    const int c0   = lane * 4;

    const float4 bv  = *reinterpret_cast<const float4*>(b1 + c0);
    const float4 gm  = *reinterpret_cast<const float4*>(gamma + c0);
    const float4 be  = *reinterpret_cast<const float4*>(beta + c0);
    const float4 w2v = *reinterpret_cast<const float4*>(W2 + c0);
    const float  b2v = b2[0];

#pragma unroll
    for (int t = 0; t < 4; ++t) {
        const int row = t0 + wave * 4 + t;
        float4 h = *reinterpret_cast<const float4*>(hbuf + (size_t)row * DD + c0);
        h.x += bv.x; h.y += bv.y; h.z += bv.z; h.w += bv.w;

        float s1 = h.x + h.y + h.z + h.w;
        float s2 = h.x * h.x + h.y * h.y + h.z * h.z + h.w * h.w;
#pragma unroll
        for (int off = 32; off > 0; off >>= 1) {
            s1 += __shfl_xor(s1, off, 64);
            s2 += __shfl_xor(s2, off, 64);
        }
        const float mean = s1 * (1.f / DD);
        const float var  = s2 * (1.f / DD) - mean * mean;
        const float inv  = rsqrtf(var + 1e-5f);

        const float n0 = (h.x - mean) * inv * gm.x + be.x;
        const float n1 = (h.y - mean) * inv * gm.y + be.y;
        const float n2 = (h.z - mean) * inv * gm.z + be.z;
        const float n3 = (h.w - mean) * inv * gm.w + be.w;
        const float kq = 0.70710678118654752f;
        const float g0 = 0.5f * n0 * (1.f + erff(n0 * kq));
        const float g1 = 0.5f * n1 * (1.f + erff(n1 * kq));
        const float g2 = 0.5f * n2 * (1.f + erff(n2 * kq));
        const float g3 = 0.5f * n3 * (1.f + erff(n3 * kq));
        float sc = g0 * w2v.x + g1 * w2v.y + g2 * w2v.z + g3 * w2v.w;
#pragma unroll
        for (int off = 32; off > 0; off >>= 1) sc += __shfl_xor(sc, off, 64);
        if (lane == 0) scores[row] = sc + b2v;
    }
}

// ====== Kernel 3 (r16 verbatim, PASSED): pool with inline softmax-numerator ======
__global__ __launch_bounds__(256) void pool_e_kernel(
    const float* __restrict__ doc, const float* __restrict__ mapping,
    const float* __restrict__ scores, float* __restrict__ part,
    float* __restrict__ zpart)
{
    __shared__ float w_lds[NT][SCH];   // 4 KiB
    __shared__ float z_s[NT];

    const int blk   = blockIdx.x;
    const int c     = blk % SC;
    const int bt    = blk / SC;
    const int ntile = bt & 15;
    const int b     = bt >> 4;
    const int s0    = c * SCH;
    const int tid = threadIdx.x, wave = tid >> 6, lane = tid & 63;

    {
        const int nl = wave * 2 + (lane >> 5);
        const int g  = b * NN + ntile * NT + nl;
        const float4 mp = reinterpret_cast<const float4*>(mapping + (size_t)g * SS + s0)[lane & 31];
        const float4 sv = reinterpret_cast<const float4*>(scores + (size_t)b * SS + s0)[lane & 31];
        float4 e;
        e.x = (mp.x > 0.5f) ? __expf(sv.x) : 0.f;
        e.y = (mp.y > 0.5f) ? __expf(sv.y) : 0.f;
        e.z = (mp.z > 0.5f) ? __expf(sv.z) : 0.f;
        e.w = (mp.w > 0.5f) ? __expf(sv.w) : 0.f;
        reinterpret_cast<float4*>(&w_lds[nl][0])[lane & 31] = e;
        float z = e.x + e.y + e.z + e.w;
#pragma unroll
        for (int off = 16; off > 0; off >>= 1) z += __shfl_xor(z, off, 64);
        if ((lane & 31) == 0) z_s[nl] = z;
    }
    __syncthreads();

    float acc[NT];
#pragma unroll
    for (int n = 0; n < NT; ++n) acc[n] = 0.f;
    const float* docb = doc + ((size_t)b * SS + s0) * DD;

    float d0 = docb[(size_t)0 * DD + tid], d1 = docb[(size_t)1 * DD + tid];
    float d2 = docb[(size_t)2 * DD + tid], d3 = docb[(size_t)3 * DD + tid];
    for (int s4 = 0; s4 < SCH - 4; s4 += 4) {
        const float n0 = docb[(size_t)(s4 + 4) * DD + tid];
        const float n1 = docb[(size_t)(s4 + 5) * DD + tid];
        const float n2 = docb[(size_t)(s4 + 6) * DD + tid];
        const float n3 = docb[(size_t)(s4 + 7) * DD + tid];
#pragma unroll
        for (int n = 0; n < NT; ++n) {
            const float4 wv = *reinterpret_cast<const float4*>(&w_lds[n][s4]);
            acc[n] = fmaf(wv.x, d0, acc[n]);
            acc[n] = fmaf(wv.y, d1, acc[n]);
            acc[n] = fmaf(wv.z, d2, acc[n]);
            acc[n] = fmaf(wv.w, d3, acc[n]);
        }
        d0 = n0; d1 = n1; d2 = n2; d3 = n3;
    }
    {
        const int s4 = SCH - 4;
#pragma unroll
        for (int n = 0; n < NT; ++n) {
            const float4 wv = *reinterpret_cast<const float4*>(&w_lds[n][s4]);
            acc[n] = fmaf(wv.x, d0, acc[n]);
            acc[n] = fmaf(wv.y, d1, acc[n]);
            acc[n] = fmaf(wv.z, d2, acc[n]);
            acc[n] = fmaf(wv.w, d3, acc[n]);
        }
    }

    float* p = part + (size_t)blk * (NT * DD);
#pragma unroll
    for (int n = 0; n < NT; ++n) p[(size_t)n * DD + tid] = acc[n];
    if (tid < NT) zpart[(size_t)blk * NT + tid] = z_s[tid];
}

// ---------------- Kernel 4 (r16 verbatim, PASSED): reduce + divide ----------------
__global__ __launch_bounds__(256) void reduce_div_kernel(
    const float* __restrict__ part, const float* __restrict__ zpart,
    float* __restrict__ out)
{
    const int o = blockIdx.x * 256 + threadIdx.x;
    const int d = o & 255;
    const int g = o >> 8;
    const int b = g >> 7;
    const int n = g & 127;
    const int ntile = n >> 3, nl = n & 7;
    const int bp0 = (b * 16 + ntile) * SC;
    float s = 0.f, z = 0.f;
#pragma unroll
    for (int c = 0; c < SC; ++c) {
        const int bp = bp0 + c;
        s += part[(size_t)bp * (NT * DD) + (size_t)nl * DD + d];
        z += zpart[(size_t)bp * NT + nl];
    }
    out[o] = (z > 0.f) ? (s / z) : 0.f;
}

// ================= Fallback path (tiny ws): r5/r16 verified kernels =================
__global__ __launch_bounds__(256) void scorer_kernel(
    const float* __restrict__ doc, const float* __restrict__ W1,
    const float* __restrict__ b1, const float* __restrict__ gamma,
    const float* __restrict__ beta, const float* __restrict__ W2,
    const float* __restrict__ b2, float* __restrict__ scores)
{
    __shared__ float xs[TOK][DD];
    __shared__ float w1s[KC][DD];

    const int tid  = threadIdx.x;
    const int wave = tid >> 6, lane = tid & 63;
    const int t0   = blockIdx.x * TOK;
    const int c0   = lane * 4;

    {
        const float4* src = reinterpret_cast<const float4*>(doc + (size_t)t0 * DD);
        float4* dst = reinterpret_cast<float4*>(&xs[0][0]);
#pragma unroll
        for (int r = 0; r < 4; ++r) dst[tid + 256 * r] = src[tid + 256 * r];
    }

    float4 acc[4];
    {
        const float4 bv = *reinterpret_cast<const float4*>(b1 + c0);
#pragma unroll
        for (int t = 0; t < 4; ++t) acc[t] = bv;
    }
    const float* xw = &xs[wave * 4][0];

    for (int kc = 0; kc < DD / KC; ++kc) {
        __syncthreads();
        {
            const float4* wsrc = reinterpret_cast<const float4*>(W1 + (size_t)kc * KC * DD);
            float4* wdst = reinterpret_cast<float4*>(&w1s[0][0]);
#pragma unroll
            for (int r = 0; r < 16; ++r) wdst[tid + 256 * r] = wsrc[tid + 256 * r];
        }
        __syncthreads();
#pragma unroll 4
        for (int k4 = 0; k4 < KC / 4; ++k4) {
            const int kb = k4 * 4;
            const float4 w0 = *reinterpret_cast<const float4*>(&w1s[kb + 0][c0]);
            const float4 w1 = *reinterpret_cast<const float4*>(&w1s[kb + 1][c0]);
            const float4 w2 = *reinterpret_cast<const float4*>(&w1s[kb + 2][c0]);
            const float4 w3 = *reinterpret_cast<const float4*>(&w1s[kb + 3][c0]);
#pragma unroll
            for (int t = 0; t < 4; ++t) {
                const float4 xv = *reinterpret_cast<const float4*>(xw + (size_t)t * DD + kc * KC + kb);
                acc[t].x = fmaf(xv.x, w0.x, acc[t].x);
                acc[t].y = fmaf(xv.x, w0.y, acc[t].y);
                acc[t].z = fmaf(xv.x, w0.z, acc[t].z);
                acc[t].w = fmaf(xv.x, w0.w, acc[t].w);
                acc[t].x = fmaf(xv.y, w1.x, acc[t].x);
                acc[t].y = fmaf(xv.y, w1.y, acc[t].y);
                acc[t].z = fmaf(xv.y, w1.z, acc[t].z);
                acc[t].w = fmaf(xv.y, w1.w, acc[t].w);
                acc[t].x = fmaf(xv.z, w2.x, acc[t].x);
                acc[t].y = fmaf(xv.z, w2.y, acc[t].y);
                acc[t].z = fmaf(xv.z, w2.z, acc[t].z);
                acc[t].w = fmaf(xv.z, w2.w, acc[t].w);
                acc[t].x = fmaf(xv.w, w3.x, acc[t].x);
                acc[t].y = fmaf(xv.w, w3.y, acc[t].y);
                acc[t].z = fmaf(xv.w, w3.z, acc[t].z);
                acc[t].w = fmaf(xv.w, w3.w, acc[t].w);
            }
        }
    }

    const float4 gm = *reinterpret_cast<const float4*>(gamma + c0);
    const float4 be = *reinterpret_cast<const float4*>(beta + c0);
    const float4 w2v = *reinterpret_cast<const float4*>(W2 + c0);
    const float b2v = b2[0];

#pragma unroll
    for (int t = 0; t < 4; ++t) {
        float s1 = acc[t].x + acc[t].y + acc[t].z + acc[t].w;
        float s2 = acc[t].x * acc[t].x + acc[t].y * acc[t].y
                 + acc[t].z * acc[t].z + acc[t].w * acc[t].w;
#pragma unroll
        for (int off = 32; off > 0; off >>= 1) {
            s1 += __shfl_xor(s1, off, 64);
            s2 += __shfl_xor(s2, off, 64);
        }
        const float mean = s1 * (1.f / DD);
        const float var  = s2 * (1.f / DD) - mean * mean;
        const float inv  = rsqrtf(var + 1e-5f);
        float n0 = (acc[t].x - mean) * inv * gm.x + be.x;
        float n1 = (acc[t].y - mean) * inv * gm.y + be.y;
        float n2 = (acc[t].z - mean) * inv * gm.z + be.z;
        float n3 = (acc[t].w - mean) * inv * gm.w + be.w;
        const float kq = 0.70710678118654752f;
        float g0 = 0.5f * n0 * (1.f + erff(n0 * kq));
        float g1 = 0.5f * n1 * (1.f + erff(n1 * kq));
        float g2 = 0.5f * n2 * (1.f + erff(n2 * kq));
        float g3 = 0.5f * n3 * (1.f + erff(n3 * kq));
        float sc = g0 * w2v.x + g1 * w2v.y + g2 * w2v.z + g3 * w2v.w;
#pragma unroll
        for (int off = 32; off > 0; off >>= 1) sc += __shfl_xor(sc, off, 64);
        if (lane == 0) scores[t0 + wave * 4 + t] = sc + b2v;
    }
}

extern "C" void kernel_launch(void* const* d_in, const int* in_sizes, int n_in,
                              void* d_out, int out_size, void* d_ws, size_t ws_size,
                              hipStream_t stream) {
    const float* doc     = (const float*)d_in[0];  // (B,S,D)
    const float* mapping = (const float*)d_in[1];  // (B,N,S)
    // d_in[2] = nodes_len (unused)
    const float* W1    = (const float*)d_in[3];    // (D,D)
    const float* b1    = (const float*)d_in[4];    // (D)
    const float* gamma = (const float*)d_in[5];    // (D)
    const float* beta  = (const float*)d_in[6];    // (D)
    const float* W2    = (const float*)d_in[7];    // (D,1)
    const float* b2    = (const float*)d_in[8];    // (1)
    float* out = (float*)d_out;                    // (B,N,D)

    char* base = (char*)d_ws;
    size_t off = 0;
    float* scores = (float*)(base + off); off += (size_t)BB * SS * 4;                   // 32 KiB
    float* part   = (float*)(base + off); off += (size_t)BB * 16 * SC * NT * DD * 4;    // 8 MiB
    float* zpart  = (float*)(base + off); off += (size_t)BB * 16 * SC * NT * 4;         // 32 KiB
    float* hbuf   = (float*)(base + off); off += (size_t)BB * SS * DD * 4;              // 8 MiB
    unsigned short* w1t_hi = (unsigned short*)(base + off); off += (size_t)DD * DD * 2; // 128 KiB
    unsigned short* w1t_lo = (unsigned short*)(base + off); off += (size_t)DD * DD * 2; // 128 KiB
    const size_t need = off;
    const size_t need_min = (size_t)(BB * SS) * 4
                          + (size_t)BB * 16 * SC * NT * DD * 4
                          + (size_t)BB * 16 * SC * NT * 4;

    if (ws_size >= need) {
        split_w1t_kernel<<<16, 256, 0, stream>>>(W1, w1t_hi, w1t_lo);
        scorer_gemm_staged<<<1024, 256, 0, stream>>>(doc, w1t_hi, w1t_lo, hbuf);
        combine_kernel<<<512, 256, 0, stream>>>(hbuf, b1, gamma, beta, W2, b2, scores);
        pool_e_kernel<<<BB * 16 * SC, 256, 0, stream>>>(doc, mapping, scores, part, zpart);
        reduce_div_kernel<<<(BB * NN * DD) / 256, 256, 0, stream>>>(part, zpart, out);
    } else if (ws_size >= need_min) {
        scorer_kernel<<<BB * SS / TOK, 256, 0, stream>>>(doc, W1, b1, gamma, beta, W2, b2, scores);
        pool_e_kernel<<<BB * 16 * SC, 256, 0, stream>>>(doc, mapping, scores, part, zpart);
        reduce_div_kernel<<<(BB * NN * DD) / 256, 256, 0, stream>>>(part, zpart, out);
    }
}